// Round 7
// baseline (655.658 us; speedup 1.0000x reference)
//
#include <hip/hip_runtime.h>
#include <hip/hip_bf16.h>

typedef float f32x4 __attribute__((ext_vector_type(4)));
typedef short short8 __attribute__((ext_vector_type(8)));
typedef __bf16 bf16x8 __attribute__((ext_vector_type(8)));

#define N_TOT 16384
#define FEATS 256
#define BM 64
#define BK 64
#define KSPLIT 4
#define CHUNK (N_TOT / KSPLIT)   // 4096
#define NSTEPS (CHUNK / BK)      // 64

static __device__ __forceinline__ ushort f2bf(float f) {
  union { __hip_bfloat16 b; ushort u; } cv;
  cv.b = __float2bfloat16(f);
  return cv.u;
}
static __device__ __forceinline__ float bf2f(ushort u) {
  union { unsigned int i; float f; } c;
  c.i = ((unsigned int)u) << 16;
  return c.f;
}
static __device__ __forceinline__ void gload_lds16(const void* g, void* l) {
  __builtin_amdgcn_global_load_lds((const __attribute__((address_space(1))) unsigned int*)g,
                                   (__attribute__((address_space(3))) unsigned int*)l,
                                   16, 0, 0);
}
static __device__ __forceinline__ bf16x8 cvt8(float4 a, float4 b) {
  short8 r = { (short)f2bf(a.x), (short)f2bf(a.y), (short)f2bf(a.z), (short)f2bf(a.w),
               (short)f2bf(b.x), (short)f2bf(b.y), (short)f2bf(b.z), (short)f2bf(b.w) };
  return __builtin_bit_cast(bf16x8, r);
}

// ---- K0: F2T[o][m] = (features @ W^T)^T in bf16 (associativity fusion; r6-verified)
__global__ __launch_bounds__(64) void k_f2t(const float* __restrict__ feat,
                                            const float* __restrict__ W,
                                            ushort* __restrict__ F2T) {
  const int lane = threadIdx.x;
  const int rsel = lane & 15, kg = lane >> 4;
  const int mb = blockIdx.x >> 1;
  const int o0 = (blockIdx.x & 1) * 128;
  const int m0 = mb * 16;

  f32x4 acc[8] = {};
#pragma unroll
  for (int ks = 0; ks < 8; ++ks) {
    const int k0 = ks * 32 + kg * 8;
    const float4 fa0 = *(const float4*)(feat + (size_t)(m0 + rsel) * FEATS + k0);
    const float4 fa1 = *(const float4*)(feat + (size_t)(m0 + rsel) * FEATS + k0 + 4);
    const bf16x8 af = cvt8(fa0, fa1);
#pragma unroll
    for (int of = 0; of < 8; ++of) {
      const float4 wb0 = *(const float4*)(W + (size_t)(o0 + of * 16 + rsel) * FEATS + k0);
      const float4 wb1 = *(const float4*)(W + (size_t)(o0 + of * 16 + rsel) * FEATS + k0 + 4);
      acc[of] = __builtin_amdgcn_mfma_f32_16x16x32_bf16(af, cvt8(wb0, wb1), acc[of], 0, 0, 0);
    }
  }
#pragma unroll
  for (int of = 0; of < 8; ++of) {
    ushort4 ov = { f2bf(acc[of][0]), f2bf(acc[of][1]), f2bf(acc[of][2]), f2bf(acc[of][3]) };
    *(ushort4*)(F2T + (size_t)(o0 + of * 16 + rsel) * N_TOT + m0 + kg * 4) = ov;
  }
}

// ---- K1: parts[kb] = graph[:, kchunk] @ F2[kchunk, :]
// 512 thr = 8 waves (2M x 4N), wave tile 32x64, BM=64, BK=64 (2 halves of 32).
// A: global -> VGPR fragments, per-wave counted prefetch 1 step ahead (no barrier
// coupling; L1 dedups x4 wn-redundancy). B: glds -> LDS half-buffers, staged one
// half-step ahead. Steady-state vmcnt(4) at each half-entry -- never drains.
__global__ __launch_bounds__(512, 4) void k_gemm1(const float* __restrict__ graph,
                                                  const ushort* __restrict__ F2T,
                                                  ushort* __restrict__ parts) {
  __shared__ char Bl[2][FEATS * 64];   // 2 x 16 KiB
  const int tid = threadIdx.x, lane = tid & 63, w = tid >> 6;
  const int wm = w >> 2, wn = w & 3;
  const int rsel = lane & 15, kg = lane >> 4;

  const int b = blockIdx.x, xcd = b & 7, kb = xcd >> 1;   // kb pinned to XCD pair
  const int mi = ((b >> 3) << 1) | (xcd & 1);             // 0..255
  const size_t m0 = (size_t)mi * BM;
  const int kbase = kb * CHUNK;
  const int ph = ((b >> 3) * 13) & (NSTEPS - 1);          // k-phase rotation

  const float* arow0 = graph + (m0 + wm * 32 + rsel) * (size_t)N_TOT + kbase;
  const float* arow1 = arow0 + (size_t)16 * N_TOT;

  // stage B half h of tile t into Bl[buf]: 2 glds/wave, 16 rows x 64B each,
  // XOR involution on the 16B chunk (bank-spread; rule #21 both-sides pairing)
  auto stageB = [&](int buf, int t, int h) {
    const int k0 = kbase + t * BK + h * 32;
    char* dst = &Bl[buf][0];
#pragma unroll
    for (int j = 0; j < 2; ++j) {
      const int r0 = w * 32 + j * 16;
      const int r = r0 + (lane >> 2);
      const int cg = (lane & 3) ^ ((r >> 1) & 3);
      gload_lds16(F2T + (size_t)r * N_TOT + k0 + cg * 8, dst + r0 * 64);
    }
  };
  // issue A fragment loads for half h of tile t into regs (4 dwordx4/lane)
  auto issueA = [&](float4 (&A)[8], int base, int t, int h) {
    const int ko = t * BK + h * 32 + kg * 8;
    A[base + 0] = *(const float4*)(arow0 + ko);
    A[base + 1] = *(const float4*)(arow0 + ko + 4);
    A[base + 2] = *(const float4*)(arow1 + ko);
    A[base + 3] = *(const float4*)(arow1 + ko + 4);
  };

  f32x4 acc[2][4] = {};
  auto compute = [&](int buf, float4 (&A)[8], int base) {
    const char* Bb = &Bl[buf][0];
    short8 bfr[4];
#pragma unroll
    for (int nf = 0; nf < 4; ++nf) {
      const int row = wn * 64 + nf * 16 + rsel;
      const int c = kg ^ ((row >> 1) & 3);
      bfr[nf] = *(const short8*)(Bb + row * 64 + c * 16);
    }
#pragma unroll
    for (int mf = 0; mf < 2; ++mf) {
      const bf16x8 af = cvt8(A[base + mf * 2], A[base + mf * 2 + 1]);
#pragma unroll
      for (int nf = 0; nf < 4; ++nf)
        acc[mf][nf] = __builtin_amdgcn_mfma_f32_16x16x32_bf16(
            af, __builtin_bit_cast(bf16x8, bfr[nf]), acc[mf][nf], 0, 0, 0);
    }
  };

  auto tileof = [&](int s) { return (s + ph) & (NSTEPS - 1); };

  float4 aA[8], aB[8];   // step-parity A fragment registers (h0: [0..3], h1: [4..7])

  // prologue: B(0,h0) staged; A(0,h0), A(0,h1) in flight
  stageB(0, tileof(0), 0);
  __builtin_amdgcn_sched_barrier(0);
  issueA(aA, 0, tileof(0), 0);
  __builtin_amdgcn_sched_barrier(0);
  issueA(aA, 4, tileof(0), 1);
  __builtin_amdgcn_sched_barrier(0);

  // per step s: h0 { wait; bar; stage B(s,h1); issue A(s+1,h0); mfma } then
  //             h1 { wait; bar; stage B(s+1,h0); issue A(s+1,h1); mfma }.
  // Queue at each entry: [B(2 glds), A(4 loads)] -> vmcnt(4) = B + prior-A done,
  // newest A half stays in flight. Tail wraps via tileof (harmless re-reads).
  auto body = [&](int s, float4 (&Ac)[8], float4 (&An)[8]) {
    const int tn = tileof(s + 1);
    asm volatile("s_waitcnt vmcnt(4)" ::: "memory");
    __builtin_amdgcn_s_barrier();
    stageB(1, tileof(s), 1);
    __builtin_amdgcn_sched_barrier(0);
    issueA(An, 0, tn, 0);
    __builtin_amdgcn_sched_barrier(0);
    compute(0, Ac, 0);

    asm volatile("s_waitcnt vmcnt(4)" ::: "memory");
    __builtin_amdgcn_s_barrier();
    stageB(0, tn, 0);
    __builtin_amdgcn_sched_barrier(0);
    issueA(An, 4, tn, 1);
    __builtin_amdgcn_sched_barrier(0);
    compute(1, Ac, 4);
  };

  for (int s = 0; s < NSTEPS; s += 2) {
    body(s, aA, aB);
    body(s + 1, aB, aA);
  }

  // epilogue: bf16 partial store. C/D: col=lane&15, row=(lane>>4)*4+j
  ushort* p = parts + (size_t)kb * N_TOT * FEATS;
#pragma unroll
  for (int mf = 0; mf < 2; ++mf)
#pragma unroll
    for (int nf = 0; nf < 4; ++nf)
#pragma unroll
      for (int j = 0; j < 4; ++j) {
        const int row = wm * 32 + mf * 16 + kg * 4 + j;
        const int col = wn * 64 + nf * 16 + rsel;
        p[(m0 + row) * FEATS + col] = f2bf(acc[mf][nf][j]);
      }
}

// ---- K2: out = relu(sum_kb parts[kb] + b)
__global__ __launch_bounds__(256) void k_reduce(const ushort* __restrict__ parts,
                                                const float* __restrict__ bias,
                                                float* __restrict__ out) {
  const size_t base = ((size_t)blockIdx.x * 256 + threadIdx.x) * 8;
  const int o0 = (int)(base & (FEATS - 1));
  float s[8] = {0, 0, 0, 0, 0, 0, 0, 0};
#pragma unroll
  for (int p = 0; p < KSPLIT; ++p) {
    const short8 v = *(const short8*)(parts + (size_t)p * N_TOT * FEATS + base);
#pragma unroll
    for (int j = 0; j < 8; ++j) s[j] += bf2f((ushort)v[j]);
  }
  const float4 b0 = *(const float4*)(bias + o0);
  const float4 b1 = *(const float4*)(bias + o0 + 4);
  float4 r0 = { fmaxf(s[0] + b0.x, 0.f), fmaxf(s[1] + b0.y, 0.f),
                fmaxf(s[2] + b0.z, 0.f), fmaxf(s[3] + b0.w, 0.f) };
  float4 r1 = { fmaxf(s[4] + b1.x, 0.f), fmaxf(s[5] + b1.y, 0.f),
                fmaxf(s[6] + b1.z, 0.f), fmaxf(s[7] + b1.w, 0.f) };
  *(float4*)(out + base) = r0;
  *(float4*)(out + base + 4) = r1;
}

extern "C" void kernel_launch(void* const* d_in, const int* in_sizes, int n_in,
                              void* d_out, int out_size, void* d_ws, size_t ws_size,
                              hipStream_t stream) {
  const float* graph = (const float*)d_in[0];
  const float* feat  = (const float*)d_in[1];
  const float* W     = (const float*)d_in[2];
  const float* bias  = (const float*)d_in[3];
  float* out = (float*)d_out;

  char* ws = (char*)d_ws;
  ushort* F2T   = (ushort*)ws;                                 // 8 MiB
  ushort* parts = (ushort*)(ws + (size_t)8 * 1024 * 1024);     // 32 MiB

  k_f2t<<<dim3(2048), 64, 0, stream>>>(feat, W, F2T);
  k_gemm1<<<dim3((N_TOT / BM) * KSPLIT), 512, 0, stream>>>(graph, F2T, parts);
  k_reduce<<<dim3(N_TOT * FEATS / 8 / 256), 256, 0, stream>>>(parts, bias, out);
}

// Round 8
// 298.773 us; speedup vs baseline: 2.1945x; 2.1945x over previous
//
#include <hip/hip_runtime.h>
#include <hip/hip_bf16.h>

typedef float f32x4 __attribute__((ext_vector_type(4)));
typedef short short8 __attribute__((ext_vector_type(8)));
typedef __bf16 bf16x8 __attribute__((ext_vector_type(8)));

#define N_TOT 16384
#define FEATS 256
#define BM 128
#define BK 64
#define KSPLIT 2
#define CHUNK (N_TOT / KSPLIT)   // 8192
#define NSTEPS (CHUNK / BK)      // 128
#define LDSA_BYTES (BM * 256)    // fp32 A tile, 256B rows, 32 KiB
#define LDSB_BYTES (FEATS * 128) // bf16 B tile, 128B rows, 32 KiB
#define TILE_BYTES (LDSA_BYTES + LDSB_BYTES)

static __device__ __forceinline__ ushort f2bf(float f) {
  union { __hip_bfloat16 b; ushort u; } cv;
  cv.b = __float2bfloat16(f);
  return cv.u;
}
static __device__ __forceinline__ float bf2f(ushort u) {
  union { unsigned int i; float f; } c;
  c.i = ((unsigned int)u) << 16;
  return c.f;
}
static __device__ __forceinline__ void gload_lds16(const void* g, void* l) {
  __builtin_amdgcn_global_load_lds((const __attribute__((address_space(1))) unsigned int*)g,
                                   (__attribute__((address_space(3))) unsigned int*)l,
                                   16, 0, 0);
}
static __device__ __forceinline__ bf16x8 cvt8(float4 a, float4 b) {
  short8 r = { (short)f2bf(a.x), (short)f2bf(a.y), (short)f2bf(a.z), (short)f2bf(a.w),
               (short)f2bf(b.x), (short)f2bf(b.y), (short)f2bf(b.z), (short)f2bf(b.w) };
  return __builtin_bit_cast(bf16x8, r);
}

// ---- K0: F2T[o][m] = (features @ W^T)^T in bf16 (associativity fusion; r6/r7-verified)
__global__ __launch_bounds__(64) void k_f2t(const float* __restrict__ feat,
                                            const float* __restrict__ W,
                                            ushort* __restrict__ F2T) {
  const int lane = threadIdx.x;
  const int rsel = lane & 15, kg = lane >> 4;
  const int mb = blockIdx.x >> 1;
  const int o0 = (blockIdx.x & 1) * 128;
  const int m0 = mb * 16;

  f32x4 acc[8] = {};
#pragma unroll
  for (int ks = 0; ks < 8; ++ks) {
    const int k0 = ks * 32 + kg * 8;
    const float4 fa0 = *(const float4*)(feat + (size_t)(m0 + rsel) * FEATS + k0);
    const float4 fa1 = *(const float4*)(feat + (size_t)(m0 + rsel) * FEATS + k0 + 4);
    const bf16x8 af = cvt8(fa0, fa1);
#pragma unroll
    for (int of = 0; of < 8; ++of) {
      const float4 wb0 = *(const float4*)(W + (size_t)(o0 + of * 16 + rsel) * FEATS + k0);
      const float4 wb1 = *(const float4*)(W + (size_t)(o0 + of * 16 + rsel) * FEATS + k0 + 4);
      acc[of] = __builtin_amdgcn_mfma_f32_16x16x32_bf16(af, cvt8(wb0, wb1), acc[of], 0, 0, 0);
    }
  }
#pragma unroll
  for (int of = 0; of < 8; ++of) {
    ushort4 ov = { f2bf(acc[of][0]), f2bf(acc[of][1]), f2bf(acc[of][2]), f2bf(acc[of][3]) };
    *(ushort4*)(F2T + (size_t)(o0 + of * 16 + rsel) * N_TOT + m0 + kg * 4) = ov;
  }
}

// ---- K1: parts[kb] = graph[:, kchunk] @ F2[kchunk, :]
// 512 thr = 8 waves (2M x 4N), wave tile 64x64. BK=64: every glds covers 256B (A)
// / 128B (B) per row-visit -- the DRAM-granularity lever. A fp32 + B bf16 both
// glds -> LDS, 2-deep counted vmcnt(8) (one full stage in flight, never drained).
__global__ __launch_bounds__(512, 2) void k_gemm1(const float* __restrict__ graph,
                                                  const ushort* __restrict__ F2T,
                                                  ushort* __restrict__ parts) {
  __shared__ char lds[2][TILE_BYTES];   // 128 KiB -> 1 block/CU
  const int tid = threadIdx.x, lane = tid & 63, w = tid >> 6;
  const int wm = w >> 2, wn = w & 3;
  const int rsel = lane & 15, kg = lane >> 4;

  const int b = blockIdx.x;            // 256 blocks; b&7 = XCD (round-robin)
  const int kb = b & 1;                // kb chunk pinned to 4-XCD group (4MB = L2)
  const int mi = b >> 1;               // 0..127
  const size_t m0 = (size_t)mi * BM;
  const int kbase = kb * CHUNK;
  const int ph = (b * 53) & (NSTEPS - 1);   // per-block k-phase rotation

  // stage K-tile t into buf bf: 8 glds/wave (4 A + 4 B). XOR involution on the
  // GLOBAL 16B-chunk index, linear LDS dest (rule #21). A addressing = r6-verified.
  auto stage = [&](int bf, int t) {
    const int k0 = kbase + t * BK;
    char* ldsA = &lds[bf][0];
    char* ldsB = &lds[bf][LDSA_BYTES];
#pragma unroll
    for (int j = 0; j < 4; ++j) {                    // A: 4 rows x 256B per instr
      const int r0 = j * 32 + w * 4;
      const int row = r0 + (lane >> 4);
      const int c = (lane & 15) ^ (row & 15);        // 16B chunk within 256B row
      gload_lds16(graph + (m0 + row) * (size_t)N_TOT + k0 + c * 4, ldsA + r0 * 256);
    }
#pragma unroll
    for (int j = 0; j < 4; ++j) {                    // B: 8 rows x 128B per instr
      const int r0 = w * 32 + j * 8;
      const int row = r0 + (lane >> 3);
      const int c = (lane & 7) ^ (row & 7);          // 16B chunk within 128B row
      gload_lds16(F2T + (size_t)row * N_TOT + k0 + c * 8, ldsB + r0 * 128);
    }
  };

  f32x4 acc[4][4] = {};

  auto compute = [&](int bf) {
    const char* Ab = &lds[bf][0];
    const char* Bb = &lds[bf][LDSA_BYTES];
#pragma unroll
    for (int ksub = 0; ksub < 2; ++ksub) {
      short8 bfr[4];
#pragma unroll
      for (int nf = 0; nf < 4; ++nf) {
        const int row = wn * 64 + nf * 16 + rsel;
        const int c = (ksub * 4 + kg) ^ (row & 7);   // bf16 16B chunk
        bfr[nf] = *(const short8*)(Bb + row * 128 + c * 16);
      }
#pragma unroll
      for (int mf = 0; mf < 4; ++mf) {
        const int row = wm * 64 + mf * 16 + rsel;
        const int cg = ksub * 8 + kg * 2;            // fp32 16B-chunk index
        const float4 a0 = *(const float4*)(Ab + row * 256 + ((cg)     ^ (row & 15)) * 16);
        const float4 a1 = *(const float4*)(Ab + row * 256 + ((cg + 1) ^ (row & 15)) * 16);
        const bf16x8 af = cvt8(a0, a1);
#pragma unroll
        for (int nf = 0; nf < 4; ++nf)
          acc[mf][nf] = __builtin_amdgcn_mfma_f32_16x16x32_bf16(
              af, __builtin_bit_cast(bf16x8, bfr[nf]), acc[mf][nf], 0, 0, 0);
      }
    }
  };

  auto tileof = [&](int s) { return (s + ph) & (NSTEPS - 1); };

  stage(0, tileof(0));
  stage(1, tileof(1));

  for (int s = 0; s < NSTEPS - 2; ++s) {
    asm volatile("s_waitcnt vmcnt(8)" ::: "memory");   // tile-s's 8 glds done
    __builtin_amdgcn_s_barrier();
    compute(s & 1);
    __builtin_amdgcn_s_barrier();                      // all reads of buf done
    stage(s & 1, tileof(s + 2));
    __builtin_amdgcn_sched_barrier(0);
  }
  asm volatile("s_waitcnt vmcnt(8)" ::: "memory");
  __builtin_amdgcn_s_barrier();
  compute((NSTEPS - 2) & 1);
  asm volatile("s_waitcnt vmcnt(0)" ::: "memory");
  __builtin_amdgcn_s_barrier();
  compute((NSTEPS - 1) & 1);

  // epilogue: bf16 partial store. C/D: col=lane&15, row=kg*4+j
  ushort* p = parts + (size_t)kb * N_TOT * FEATS;
#pragma unroll
  for (int mf = 0; mf < 4; ++mf)
#pragma unroll
    for (int nf = 0; nf < 4; ++nf)
#pragma unroll
      for (int j = 0; j < 4; ++j) {
        const int row = wm * 64 + mf * 16 + kg * 4 + j;
        const int col = wn * 64 + nf * 16 + rsel;
        p[(m0 + row) * FEATS + col] = f2bf(acc[mf][nf][j]);
      }
}

// ---- K2: out = relu(sum_kb parts[kb] + b)
__global__ __launch_bounds__(256) void k_reduce(const ushort* __restrict__ parts,
                                                const float* __restrict__ bias,
                                                float* __restrict__ out) {
  const size_t base = ((size_t)blockIdx.x * 256 + threadIdx.x) * 8;
  const int o0 = (int)(base & (FEATS - 1));
  float s[8] = {0, 0, 0, 0, 0, 0, 0, 0};
#pragma unroll
  for (int p = 0; p < KSPLIT; ++p) {
    const short8 v = *(const short8*)(parts + (size_t)p * N_TOT * FEATS + base);
#pragma unroll
    for (int j = 0; j < 8; ++j) s[j] += bf2f((ushort)v[j]);
  }
  const float4 b0 = *(const float4*)(bias + o0);
  const float4 b1 = *(const float4*)(bias + o0 + 4);
  float4 r0 = { fmaxf(s[0] + b0.x, 0.f), fmaxf(s[1] + b0.y, 0.f),
                fmaxf(s[2] + b0.z, 0.f), fmaxf(s[3] + b0.w, 0.f) };
  float4 r1 = { fmaxf(s[4] + b1.x, 0.f), fmaxf(s[5] + b1.y, 0.f),
                fmaxf(s[6] + b1.z, 0.f), fmaxf(s[7] + b1.w, 0.f) };
  *(float4*)(out + base) = r0;
  *(float4*)(out + base + 4) = r1;
}

extern "C" void kernel_launch(void* const* d_in, const int* in_sizes, int n_in,
                              void* d_out, int out_size, void* d_ws, size_t ws_size,
                              hipStream_t stream) {
  const float* graph = (const float*)d_in[0];
  const float* feat  = (const float*)d_in[1];
  const float* W     = (const float*)d_in[2];
  const float* bias  = (const float*)d_in[3];
  float* out = (float*)d_out;

  char* ws = (char*)d_ws;
  ushort* F2T   = (ushort*)ws;                                 // 8 MiB
  ushort* parts = (ushort*)(ws + (size_t)8 * 1024 * 1024);     // 16 MiB

  k_f2t<<<dim3(2048), 64, 0, stream>>>(feat, W, F2T);
  k_gemm1<<<dim3((N_TOT / BM) * KSPLIT), 512, 0, stream>>>(graph, F2T, parts);
  k_reduce<<<dim3(N_TOT * FEATS / 8 / 256), 256, 0, stream>>>(parts, bias, out);
}